// Round 7
// baseline (808.307 us; speedup 1.0000x reference)
//
#include <hip/hip_runtime.h>

#define NPTS 1000000
#define C 64
#define B 64
#define NFINE 128            // 4*4*8 fine bins per batch
#define KTOT (64*201)        // 12864 pyramid width
#define SREP 532480          // floats per (S,cnt) replica: 64*128*64 + 64*128
#define LSTRIDE 65           // odd stride -> conflict-free LDS transpose both ways

typedef float f32x4 __attribute__((ext_vector_type(4)));   // clang vector: ok for nt builtins

// ws layout (floats):
//  replica r in [0,R): S_r @ r*SREP (524288), cnt_r @ r*SREP+524288 (8192)
//  ESUM: [B]      @ R*SREP
//  acc1: [B*256]  @ R*SREP+64        (zeroed prefix ends @ R*SREP+16448)
//  pyramid:[B*KTOT] @ R*SREP+16448

__global__ __launch_bounds__(256)
void zero_kernel(float4* __restrict__ p, int nf4) {
    int i = blockIdx.x * 256 + threadIdx.x;
    if (i < nf4) p[i] = make_float4(0.f, 0.f, 0.f, 0.f);
}

// One pass: per-point MLP -> e=exp(raw); fine-bin scatter of feats*e via
// wave-wide coalesced atomics; per-batch exp-sum.
// LOCAL=1: replica = PHYSICAL XCD id (s_getreg XCC_ID) and workgroup-scope
// atomics -> RMW serviced at the local per-XCD L2 (stays dirty in L2, no
// memory-side coherence-point write-through; r6 counters: WRITE_SIZE 281MB
// = device-scope atomics writing through). All writers of replica r are
// physically on XCD r, so L2-level atomicity suffices; kernel-end release
// publishes to finalize_kernel.
// LOCAL=0 fallback (ws too small for 8 replicas): device-scope, blockIdx&rmask.
// No per-tile __syncthreads: each wave writes/reads only its own LDS rows;
// same-wave DS ops are ordered by HW (passed r6 with absmax 3e-8).
// LDS halved vs r6 (stage 32 of the wave's 64 points per sub-phase):
// 33.5KB/block -> 4 blocks/CU -> 16 waves/CU (r6: 67KB, 8 waves, Occ 20.7%).
template<int LOCAL>
__global__ __launch_bounds__(256)
void fused_kernel(const float* __restrict__ feats,
                  const int* __restrict__ bidx,
                  const int* __restrict__ coords,
                  const float* __restrict__ aW1,
                  const float* __restrict__ ab1,
                  const float* __restrict__ aW2,
                  const float* __restrict__ ab2,
                  float* __restrict__ wsbase,
                  int rmask,
                  float* __restrict__ ESUM) {
    __shared__ float sh_es[B];
    __shared__ float lds_w[128 * LSTRIDE];     // 33.3 KB; odd stride => conflict-free
    int rep;
    if (LOCAL) {
        unsigned int xcc;
        asm volatile("s_getreg_b32 %0, hwreg(HW_REG_XCC_ID)" : "=s"(xcc));
        rep = (int)(xcc & 7u);
    } else {
        rep = blockIdx.x & rmask;
    }
    float* __restrict__ S   = wsbase + (size_t)rep * SREP;
    float* __restrict__ cnt = S + 524288;
    const int tid = threadIdx.x;
    const int lane = tid & 63;
    const int wv = tid >> 6;
    if (tid < B) sh_es[tid] = 0.f;
    __syncthreads();

    const int ntiles = (NPTS + 255) / 256;
    for (int tile = blockIdx.x; tile < ntiles; tile += gridDim.x) {
        const int p = tile * 256 + tid;
        int mybin = -1;
        f32x4 r[16];
        float e = 0.f;
        if (p < NPTS) {
            // feature row -> registers; streamed once -> non-temporal (keep L2
            // for the atomic bin replicas)
            const f32x4* fr = (const f32x4*)(feats + (size_t)p * C);
            #pragma unroll
            for (int i = 0; i < 16; ++i) r[i] = __builtin_nontemporal_load(&fr[i]);
            // MLP: h = relu(f @ aW1 + ab1); raw = h @ aW2 + ab2 (weights -> s_loads)
            float h[32];
            #pragma unroll
            for (int j = 0; j < 32; ++j) h[j] = ab1[j];
            #pragma unroll
            for (int i = 0; i < 16; ++i) {
                const float f0 = r[i].x, f1 = r[i].y, f2 = r[i].z, f3 = r[i].w;
                #pragma unroll
                for (int j = 0; j < 32; ++j) {
                    h[j] = fmaf(f0, aW1[(4*i+0)*32 + j],
                           fmaf(f1, aW1[(4*i+1)*32 + j],
                           fmaf(f2, aW1[(4*i+2)*32 + j],
                           fmaf(f3, aW1[(4*i+3)*32 + j], h[j]))));
                }
            }
            float raw = ab2[0];
            #pragma unroll
            for (int j = 0; j < 32; ++j) raw = fmaf(fmaxf(h[j], 0.f), aW2[j], raw);
            e = expf(raw);                      // softmax max-shift cancels analytically
            const int b = __builtin_nontemporal_load(&bidx[p]);
            const int cx = __builtin_nontemporal_load(&coords[3*p]);
            const int cy = __builtin_nontemporal_load(&coords[3*p+1]);
            const int cz = __builtin_nontemporal_load(&coords[3*p+2]);
            mybin = b * NFINE + ((cx >> 6) << 5) + ((cy >> 6) << 3) + (cz >> 5);
            atomicAdd(&sh_es[b], e);
        }
        // two sub-phases: stage 32 points of this wave, then wave-wide scatter
        #pragma unroll
        for (int sub = 0; sub < 2; ++sub) {
            if (mybin >= 0 && (lane >> 5) == sub) {
                float* wr = &lds_w[(wv * 32 + (lane & 31)) * LSTRIDE];
                #pragma unroll
                for (int i = 0; i < 16; ++i) {
                    wr[4*i+0] = r[i].x * e;
                    wr[4*i+1] = r[i].y * e;
                    wr[4*i+2] = r[i].z * e;
                    wr[4*i+3] = r[i].w * e;
                }
            }
            // for point q of this half, 64 lanes add 64 consecutive dwords
            #pragma unroll
            for (int q = 0; q < 32; ++q) {
                const int bq = __shfl(mybin, sub * 32 + q);  // const lane -> v_readlane
                if (bq >= 0) {
                    const float v = lds_w[(wv * 32 + q) * LSTRIDE + lane];
                    if (LOCAL)
                        __hip_atomic_fetch_add(&S[(size_t)bq * C + lane], v,
                                               __ATOMIC_RELAXED, __HIP_MEMORY_SCOPE_WORKGROUP);
                    else
                        atomicAdd(&S[(size_t)bq * C + lane], v);
                }
            }
        }
        if (mybin >= 0) {
            if (LOCAL)
                __hip_atomic_fetch_add(&cnt[mybin], 1.0f,
                                       __ATOMIC_RELAXED, __HIP_MEMORY_SCOPE_WORKGROUP);
            else
                atomicAdd(&cnt[mybin], 1.0f);
        }
    }
    __syncthreads();
    if (tid < B) atomicAdd(&ESUM[tid], sh_es[tid]);   // cross-XCD: device scope required
}

// Sum replicas, aggregate fine bins -> 4 nested levels, normalize.
__global__ __launch_bounds__(256)
void finalize_kernel(const float* __restrict__ wsbase, int R,
                     const float* __restrict__ ESUM, float* __restrict__ P) {
    __shared__ float sS[NFINE * C];             // 32 KB
    __shared__ float sc[NFINE];
    const int b = blockIdx.x;
    const int tid = threadIdx.x;
    for (int i = tid; i < NFINE * C; i += 256) {
        float s = 0.f;
        for (int r = 0; r < R; ++r) s += wsbase[(size_t)r * SREP + (size_t)b * NFINE * C + i];
        sS[i] = s;
    }
    for (int i = tid; i < NFINE; i += 256) {
        float s = 0.f;
        for (int r = 0; r < R; ++r) s += wsbase[(size_t)r * SREP + 524288 + b * NFINE + i];
        sc[i] = s;
    }
    __syncthreads();
    const float inv_es = 1.0f / ESUM[b];
    float* Pb = P + (size_t)b * KTOT;
    const int lane = tid & 63;
    const int wv = tid >> 6;
    // L3 (4,4,8) @4672 : fine bins directly
    for (int bin = wv; bin < 128; bin += 4) {
        const float c = sc[bin];
        Pb[4672 + bin*C + lane] = (c > 0.f) ? sS[bin*C + lane] * inv_es / fmaxf(c, 1.f) : 0.f;
    }
    // L2 (4,4,4) @576 : pair of fine z
    for (int bin = wv; bin < 64; bin += 4) {
        const int x = bin >> 4, y = (bin >> 2) & 3, z = bin & 3;
        const int f0 = x*32 + y*8 + 2*z;
        const float c = sc[f0] + sc[f0 + 1];
        const float s = sS[f0*C + lane] + sS[(f0+1)*C + lane];
        Pb[576 + bin*C + lane] = (c > 0.f) ? s * inv_es / fmaxf(c, 1.f) : 0.f;
    }
    // L1 (2,2,2) @64 : 2x2x4 fine bins each
    for (int bin = wv; bin < 8; bin += 4) {
        const int x = bin >> 2, y = (bin >> 1) & 1, z = bin & 1;
        float c = 0.f, s = 0.f;
        for (int dx = 0; dx < 2; ++dx)
            for (int dy = 0; dy < 2; ++dy)
                for (int dz = 0; dz < 4; ++dz) {
                    const int f = (2*x+dx)*32 + (2*y+dy)*8 + (4*z+dz);
                    c += sc[f]; s += sS[f*C + lane];
                }
        Pb[64 + bin*C + lane] = (c > 0.f) ? s * inv_es / fmaxf(c, 1.f) : 0.f;
    }
    // L0 (1,1,1) @0
    if (wv == 0) {
        float c = 0.f, s = 0.f;
        for (int f = 0; f < 128; ++f) { c += sc[f]; s += sS[f*C + lane]; }
        Pb[lane] = (c > 0.f) ? s * inv_es / fmaxf(c, 1.f) : 0.f;
    }
}

// acc partial: P[64,12864] @ W1[12864,256], split-K with atomic reduce.
__global__ __launch_bounds__(256)
void gemm1_kernel(const float* __restrict__ P, const float* __restrict__ W1,
                  float* __restrict__ acc) {
    __shared__ float sP[64 * 128];              // 32 KB chunk of pyramid
    const int jb = blockIdx.x;                  // 0..3
    const int kb = blockIdx.y;                  // 0..100
    const int k0 = kb * 128;
    const int kw = min(128, KTOT - k0);         // 128 or 64 (tail)
    const int tid = threadIdx.x;
    for (int i = tid; i < 64 * 32; i += 256) {
        const int row = i >> 5, c4 = i & 31;
        if (c4 * 4 < kw)
            *(float4*)&sP[row*128 + c4*4] =
                *(const float4*)&P[(size_t)row * KTOT + k0 + c4*4];
    }
    __syncthreads();
    const int j = jb * 64 + (tid & 63);
    const int g = tid >> 6;                     // wave id -> row offset
    float a[16];
    #pragma unroll
    for (int i = 0; i < 16; ++i) a[i] = 0.f;
    for (int k4 = 0; k4 < (kw >> 2); ++k4) {
        const int k = 4 * k4;
        const float w0 = W1[(size_t)(k0+k+0)*256 + j];
        const float w1 = W1[(size_t)(k0+k+1)*256 + j];
        const float w2 = W1[(size_t)(k0+k+2)*256 + j];
        const float w3 = W1[(size_t)(k0+k+3)*256 + j];
        #pragma unroll
        for (int i = 0; i < 16; ++i) {
            const float4 pv = *(const float4*)&sP[(g + 4*i)*128 + k];
            a[i] = fmaf(pv.x, w0, fmaf(pv.y, w1, fmaf(pv.z, w2, fmaf(pv.w, w3, a[i]))));
        }
    }
    #pragma unroll
    for (int i = 0; i < 16; ++i)
        atomicAdd(&acc[(g + 4*i)*256 + j], a[i]);
}

// out = relu(acc + pb1) @ W2 + pb2
__global__ __launch_bounds__(256)
void gemm2_kernel(const float* __restrict__ acc, const float* __restrict__ pb1,
                  const float* __restrict__ W2, const float* __restrict__ pb2,
                  float* __restrict__ out) {
    __shared__ float R[256];
    const int b = blockIdx.x, j = threadIdx.x;
    R[j] = fmaxf(acc[b*256 + j] + pb1[j], 0.f);
    __syncthreads();
    float s = pb2[j];
    #pragma unroll 8
    for (int m = 0; m < 256; ++m) s = fmaf(R[m], W2[m*256 + j], s);
    out[b*256 + j] = s;
}

extern "C" void kernel_launch(void* const* d_in, const int* in_sizes, int n_in,
                              void* d_out, int out_size, void* d_ws, size_t ws_size,
                              hipStream_t stream) {
    const float* feats  = (const float*)d_in[0];
    const int*   bidx   = (const int*)d_in[1];
    const int*   coords = (const int*)d_in[2];
    // d_in[3] = batch_size scalar (fixed 64)
    const float* aW1 = (const float*)d_in[4];
    const float* ab1 = (const float*)d_in[5];
    const float* aW2 = (const float*)d_in[6];
    const float* ab2 = (const float*)d_in[7];
    const float* pW1 = (const float*)d_in[8];
    const float* pb1 = (const float*)d_in[9];
    const float* pW2 = (const float*)d_in[10];
    const float* pb2 = (const float*)d_in[11];
    float* out = (float*)d_out;
    float* ws  = (float*)d_ws;

    // Pick replica count R (power of two <= 8) that fits ws_size. Deterministic
    // across calls (ws_size constant) -> graph-capture safe.
    int R = 8;
    while (R > 1 && ((size_t)R * SREP + 16448 + 823296) * 4 > ws_size) R >>= 1;

    float* ESUM = ws + (size_t)R * SREP;
    float* acc1 = ESUM + 64;
    float* Pyr  = acc1 + 16384;

    const int zf4 = R * (SREP / 4) + 16448 / 4;   // zeroed prefix in float4s
    hipLaunchKernelGGL(zero_kernel, dim3((zf4 + 255) / 256), dim3(256), 0, stream,
                       (float4*)ws, zf4);
    if (R == 8)
        hipLaunchKernelGGL((fused_kernel<1>), dim3(2048), dim3(256), 0, stream,
                           feats, bidx, coords, aW1, ab1, aW2, ab2, ws, 7, ESUM);
    else
        hipLaunchKernelGGL((fused_kernel<0>), dim3(2048), dim3(256), 0, stream,
                           feats, bidx, coords, aW1, ab1, aW2, ab2, ws, R - 1, ESUM);
    hipLaunchKernelGGL(finalize_kernel, dim3(64), dim3(256), 0, stream, ws, R, ESUM, Pyr);
    hipLaunchKernelGGL(gemm1_kernel, dim3(4, 101), dim3(256), 0, stream, Pyr, pW1, acc1);
    hipLaunchKernelGGL(gemm2_kernel, dim3(64), dim3(256), 0, stream, acc1, pb1, pW2, pb2, out);
}

// Round 9
// 739.393 us; speedup vs baseline: 1.0932x; 1.0932x over previous
//
#include <hip/hip_runtime.h>

#define NPTS 1000000
#define C 64
#define B 64
#define NBINS 8192           // B * 128 fine bins (4x4x8 per batch)
#define KTOT (64*201)        // 12864 pyramid width
#define NSLICE 64            // hist/place partition blocks
#define SLICE 15625          // NPTS / NSLICE exactly
#define A 1048576            // 1M-slot array stride in ws

typedef float f32x4 __attribute__((ext_vector_type(4)));

// ws layout (4B units):
//  bin:   int[1M]   @ 0      (dead after place; S[8192*64] overlays @0)
//  earr:  f32[1M]   @ A      (dead after place; Pyr[823296] overlays @A)
//  sidx:  int[1M]   @ 2A
//  sexp:  f32[1M]   @ 3A
//  hist2d:int[64][8192] @ 4A            (524288)
//  offs2d:int[64][8192] @ 4A+524288     (524288)
//  binstart: int[8193]  @ 4A+1048576
//  ESUM:  f32[64]   @ 4A+1056800
//  acc1:  f32[16384]@ 4A+1056864        (total ~20.2 MB, fits proven ws)
#define ZOFF (4*A + 1056800)             // zero ESUM+acc1 = 16448 floats

__global__ __launch_bounds__(256)
void zero_kernel(float4* __restrict__ p) {
    int i = blockIdx.x * 256 + threadIdx.x;
    if (i < 16448 / 4) p[i] = make_float4(0.f, 0.f, 0.f, 0.f);
}

// Pass 1: per-point MLP -> e = exp(raw) (softmax max-shift cancels), bin id.
// Pure streaming, no scatter, no LDS tile. ESUM via block-LDS + one wave-op.
__global__ __launch_bounds__(256)
void mlp_kernel(const float* __restrict__ feats,
                const int* __restrict__ bidx,
                const int* __restrict__ coords,
                const float* __restrict__ aW1,
                const float* __restrict__ ab1,
                const float* __restrict__ aW2,
                const float* __restrict__ ab2,
                float* __restrict__ earr,
                int* __restrict__ binarr,
                float* __restrict__ ESUM) {
    __shared__ float sh_es[B];
    const int tid = threadIdx.x;
    if (tid < B) sh_es[tid] = 0.f;
    __syncthreads();
    for (int p = blockIdx.x * 256 + tid; p < NPTS; p += gridDim.x * 256) {
        f32x4 r[16];
        const f32x4* fr = (const f32x4*)(feats + (size_t)p * C);
        #pragma unroll
        for (int i = 0; i < 16; ++i) r[i] = __builtin_nontemporal_load(&fr[i]);
        float h[32];
        #pragma unroll
        for (int j = 0; j < 32; ++j) h[j] = ab1[j];
        #pragma unroll
        for (int i = 0; i < 16; ++i) {
            const float f0 = r[i].x, f1 = r[i].y, f2 = r[i].z, f3 = r[i].w;
            #pragma unroll
            for (int j = 0; j < 32; ++j) {
                h[j] = fmaf(f0, aW1[(4*i+0)*32 + j],
                       fmaf(f1, aW1[(4*i+1)*32 + j],
                       fmaf(f2, aW1[(4*i+2)*32 + j],
                       fmaf(f3, aW1[(4*i+3)*32 + j], h[j]))));
            }
        }
        float raw = ab2[0];
        #pragma unroll
        for (int j = 0; j < 32; ++j) raw = fmaf(fmaxf(h[j], 0.f), aW2[j], raw);
        const float e = expf(raw);
        const int b  = __builtin_nontemporal_load(&bidx[p]);
        const int cx = __builtin_nontemporal_load(&coords[3*p]);
        const int cy = __builtin_nontemporal_load(&coords[3*p+1]);
        const int cz = __builtin_nontemporal_load(&coords[3*p+2]);
        earr[p]   = e;
        binarr[p] = b * 128 + ((cx >> 6) << 5) + ((cy >> 6) << 3) + (cz >> 5);
        atomicAdd(&sh_es[b], e);
    }
    __syncthreads();
    if (tid < B) atomicAdd(&ESUM[tid], sh_es[tid]);
}

// Per-slice LDS histogram (no global atomics).
__global__ __launch_bounds__(256)
void hist_kernel(const int* __restrict__ binarr, int* __restrict__ hist2d) {
    __shared__ int h[NBINS];
    const int tid = threadIdx.x;
    for (int i = tid; i < NBINS; i += 256) h[i] = 0;
    __syncthreads();
    const int lo = blockIdx.x * SLICE, hi = lo + SLICE;
    for (int p = lo + tid; p < hi; p += 256) atomicAdd(&h[binarr[p]], 1);
    __syncthreads();
    for (int i = tid; i < NBINS; i += 256) hist2d[blockIdx.x * NBINS + i] = h[i];
}

// counts[bin] = sum over slices  (written into binstart[], scanned in place by scanB)
__global__ __launch_bounds__(256)
void scanA_kernel(const int* __restrict__ hist2d, int* __restrict__ binstart) {
    const int gid = blockIdx.x * 256 + threadIdx.x;
    if (gid < NBINS) {
        int s = 0;
        for (int b = 0; b < NSLICE; ++b) s += hist2d[b * NBINS + gid];
        binstart[gid] = s;
    }
}

// exclusive scan over 8192 counts, in place; binstart[8192] = NPTS
__global__ __launch_bounds__(256)
void scanB_kernel(int* __restrict__ binstart) {
    __shared__ int c[NBINS];
    __shared__ int part[257];
    const int tid = threadIdx.x;
    for (int i = tid; i < NBINS; i += 256) c[i] = binstart[i];
    __syncthreads();
    const int base = tid * 32;
    int s = 0;
    #pragma unroll
    for (int j = 0; j < 32; ++j) s += c[base + j];
    part[tid + 1] = s;
    if (tid == 0) part[0] = 0;
    __syncthreads();
    if (tid == 0) for (int i = 1; i <= 256; ++i) part[i] += part[i - 1];
    __syncthreads();
    int off = part[tid];
    #pragma unroll
    for (int j = 0; j < 32; ++j) { const int t = c[base + j]; binstart[base + j] = off; off += t; }
    if (tid == 255) binstart[NBINS] = off;   // == NPTS
}

// offs2d[slice][bin] = binstart[bin] + sum of earlier slices' counts
__global__ __launch_bounds__(256)
void scanC_kernel(const int* __restrict__ hist2d, const int* __restrict__ binstart,
                  int* __restrict__ offs2d) {
    const int gid = blockIdx.x * 256 + threadIdx.x;
    if (gid < NBINS) {
        int off = binstart[gid];
        for (int b = 0; b < NSLICE; ++b) {
            offs2d[b * NBINS + gid] = off;
            off += hist2d[b * NBINS + gid];
        }
    }
}

// Placement: LDS cursors pre-loaded with exact global offsets -> no global atomics.
__global__ __launch_bounds__(256)
void place_kernel(const int* __restrict__ binarr, const float* __restrict__ earr,
                  const int* __restrict__ offs2d,
                  int* __restrict__ sidx, float* __restrict__ sexp) {
    __shared__ int cur[NBINS];
    const int tid = threadIdx.x;
    for (int i = tid; i < NBINS; i += 256) cur[i] = offs2d[blockIdx.x * NBINS + i];
    __syncthreads();
    const int lo = blockIdx.x * SLICE, hi = lo + SLICE;
    for (int p = lo + tid; p < hi; p += 256) {
        const int b = binarr[p];
        const int pos = atomicAdd(&cur[b], 1);       // LDS atomic only
        sidx[pos] = p;
        sexp[pos] = earr[p];
    }
}

// Segmented reduction: one wave per bin, lane = channel. Coalesced 256B row
// gathers, 4 independent FMA chains for latency cover, single plain store.
__global__ __launch_bounds__(256)
void reduce_kernel(const float* __restrict__ feats,
                   const int* __restrict__ sidx, const float* __restrict__ sexp,
                   const int* __restrict__ binstart, float* __restrict__ S) {
    const int tid = threadIdx.x;
    const int lane = tid & 63;
    const int bin = blockIdx.x * 4 + (tid >> 6);
    const int start = binstart[bin], end = binstart[bin + 1];
    float a0 = 0.f, a1 = 0.f, a2 = 0.f, a3 = 0.f;
    int k = start;
    for (; k + 3 < end; k += 4) {
        const int i0 = sidx[k],     i1 = sidx[k + 1];
        const int i2 = sidx[k + 2], i3 = sidx[k + 3];
        const float e0 = sexp[k],     e1 = sexp[k + 1];
        const float e2 = sexp[k + 2], e3 = sexp[k + 3];
        const float v0 = __builtin_nontemporal_load(feats + (size_t)i0 * C + lane);
        const float v1 = __builtin_nontemporal_load(feats + (size_t)i1 * C + lane);
        const float v2 = __builtin_nontemporal_load(feats + (size_t)i2 * C + lane);
        const float v3 = __builtin_nontemporal_load(feats + (size_t)i3 * C + lane);
        a0 = fmaf(v0, e0, a0);
        a1 = fmaf(v1, e1, a1);
        a2 = fmaf(v2, e2, a2);
        a3 = fmaf(v3, e3, a3);
    }
    for (; k < end; ++k) {
        const float v = __builtin_nontemporal_load(feats + (size_t)sidx[k] * C + lane);
        a0 = fmaf(v, sexp[k], a0);
    }
    S[(size_t)bin * C + lane] = (a0 + a1) + (a2 + a3);
}

// Aggregate fine bins -> 4 nested levels, normalize by exp-sum and counts.
__global__ __launch_bounds__(256)
void finalize_kernel(const float* __restrict__ S, const int* __restrict__ binstart,
                     const float* __restrict__ ESUM, float* __restrict__ P) {
    __shared__ float sS[128 * C];               // 32 KB
    __shared__ float sc[128];
    const int b = blockIdx.x;
    const int tid = threadIdx.x;
    for (int i = tid; i < 128 * C; i += 256) sS[i] = S[(size_t)b * 128 * C + i];
    for (int i = tid; i < 128; i += 256)
        sc[i] = (float)(binstart[b * 128 + i + 1] - binstart[b * 128 + i]);
    __syncthreads();
    const float inv_es = 1.0f / ESUM[b];
    float* Pb = P + (size_t)b * KTOT;
    const int lane = tid & 63;
    const int wv = tid >> 6;
    // L3 (4,4,8) @4672
    for (int bin = wv; bin < 128; bin += 4) {
        const float c = sc[bin];
        Pb[4672 + bin*C + lane] = (c > 0.f) ? sS[bin*C + lane] * inv_es / fmaxf(c, 1.f) : 0.f;
    }
    // L2 (4,4,4) @576
    for (int bin = wv; bin < 64; bin += 4) {
        const int x = bin >> 4, y = (bin >> 2) & 3, z = bin & 3;
        const int f0 = x*32 + y*8 + 2*z;
        const float c = sc[f0] + sc[f0 + 1];
        const float s = sS[f0*C + lane] + sS[(f0+1)*C + lane];
        Pb[576 + bin*C + lane] = (c > 0.f) ? s * inv_es / fmaxf(c, 1.f) : 0.f;
    }
    // L1 (2,2,2) @64
    for (int bin = wv; bin < 8; bin += 4) {
        const int x = bin >> 2, y = (bin >> 1) & 1, z = bin & 1;
        float c = 0.f, s = 0.f;
        for (int dx = 0; dx < 2; ++dx)
            for (int dy = 0; dy < 2; ++dy)
                for (int dz = 0; dz < 4; ++dz) {
                    const int f = (2*x+dx)*32 + (2*y+dy)*8 + (4*z+dz);
                    c += sc[f]; s += sS[f*C + lane];
                }
        Pb[64 + bin*C + lane] = (c > 0.f) ? s * inv_es / fmaxf(c, 1.f) : 0.f;
    }
    // L0 (1,1,1) @0
    if (wv == 0) {
        float c = 0.f, s = 0.f;
        for (int f = 0; f < 128; ++f) { c += sc[f]; s += sS[f*C + lane]; }
        Pb[lane] = (c > 0.f) ? s * inv_es / fmaxf(c, 1.f) : 0.f;
    }
}

// acc partial: P[64,12864] @ W1[12864,256], split-K with atomic reduce.
__global__ __launch_bounds__(256)
void gemm1_kernel(const float* __restrict__ P, const float* __restrict__ W1,
                  float* __restrict__ acc) {
    __shared__ float sP[64 * 128];
    const int jb = blockIdx.x;                  // 0..3
    const int kb = blockIdx.y;                  // 0..100
    const int k0 = kb * 128;
    const int kw = min(128, KTOT - k0);
    const int tid = threadIdx.x;
    for (int i = tid; i < 64 * 32; i += 256) {
        const int row = i >> 5, c4 = i & 31;
        if (c4 * 4 < kw)
            *(float4*)&sP[row*128 + c4*4] =
                *(const float4*)&P[(size_t)row * KTOT + k0 + c4*4];
    }
    __syncthreads();
    const int j = jb * 64 + (tid & 63);
    const int g = tid >> 6;
    float a[16];
    #pragma unroll
    for (int i = 0; i < 16; ++i) a[i] = 0.f;
    for (int k4 = 0; k4 < (kw >> 2); ++k4) {
        const int k = 4 * k4;
        const float w0 = W1[(size_t)(k0+k+0)*256 + j];
        const float w1 = W1[(size_t)(k0+k+1)*256 + j];
        const float w2 = W1[(size_t)(k0+k+2)*256 + j];
        const float w3 = W1[(size_t)(k0+k+3)*256 + j];
        #pragma unroll
        for (int i = 0; i < 16; ++i) {
            const float4 pv = *(const float4*)&sP[(g + 4*i)*128 + k];
            a[i] = fmaf(pv.x, w0, fmaf(pv.y, w1, fmaf(pv.z, w2, fmaf(pv.w, w3, a[i]))));
        }
    }
    #pragma unroll
    for (int i = 0; i < 16; ++i)
        atomicAdd(&acc[(g + 4*i)*256 + j], a[i]);
}

// out = relu(acc + pb1) @ W2 + pb2
__global__ __launch_bounds__(256)
void gemm2_kernel(const float* __restrict__ acc, const float* __restrict__ pb1,
                  const float* __restrict__ W2, const float* __restrict__ pb2,
                  float* __restrict__ out) {
    __shared__ float R[256];
    const int b = blockIdx.x, j = threadIdx.x;
    R[j] = fmaxf(acc[b*256 + j] + pb1[j], 0.f);
    __syncthreads();
    float s = pb2[j];
    #pragma unroll 8
    for (int m = 0; m < 256; ++m) s = fmaf(R[m], W2[m*256 + j], s);
    out[b*256 + j] = s;
}

extern "C" void kernel_launch(void* const* d_in, const int* in_sizes, int n_in,
                              void* d_out, int out_size, void* d_ws, size_t ws_size,
                              hipStream_t stream) {
    const float* feats  = (const float*)d_in[0];
    const int*   bidx   = (const int*)d_in[1];
    const int*   coords = (const int*)d_in[2];
    const float* aW1 = (const float*)d_in[4];
    const float* ab1 = (const float*)d_in[5];
    const float* aW2 = (const float*)d_in[6];
    const float* ab2 = (const float*)d_in[7];
    const float* pW1 = (const float*)d_in[8];
    const float* pb1 = (const float*)d_in[9];
    const float* pW2 = (const float*)d_in[10];
    const float* pb2 = (const float*)d_in[11];
    float* out = (float*)d_out;
    float* ws  = (float*)d_ws;

    int*   binarr   = (int*)ws;                     // @0 ; S overlays after place
    float* earr     = ws + A;                       // @A ; Pyr overlays after place
    int*   sidx     = (int*)(ws + 2*A);
    float* sexp     = ws + 3*A;
    int*   hist2d   = (int*)(ws + 4*A);
    int*   offs2d   = (int*)(ws + 4*A + 524288);
    int*   binstart = (int*)(ws + 4*A + 1048576);
    float* ESUM     = ws + ZOFF;
    float* acc1     = ESUM + 64;
    float* S        = ws;                           // overlay on binarr
    float* Pyr      = ws + A;                       // overlay on earr

    hipLaunchKernelGGL(zero_kernel, dim3(17), dim3(256), 0, stream, (float4*)(ws + ZOFF));
    hipLaunchKernelGGL(mlp_kernel, dim3(2048), dim3(256), 0, stream,
                       feats, bidx, coords, aW1, ab1, aW2, ab2, earr, binarr, ESUM);
    hipLaunchKernelGGL(hist_kernel, dim3(NSLICE), dim3(256), 0, stream, binarr, hist2d);
    hipLaunchKernelGGL(scanA_kernel, dim3(32), dim3(256), 0, stream, hist2d, binstart);
    hipLaunchKernelGGL(scanB_kernel, dim3(1), dim3(256), 0, stream, binstart);
    hipLaunchKernelGGL(scanC_kernel, dim3(32), dim3(256), 0, stream, hist2d, binstart, offs2d);
    hipLaunchKernelGGL(place_kernel, dim3(NSLICE), dim3(256), 0, stream,
                       binarr, earr, offs2d, sidx, sexp);
    hipLaunchKernelGGL(reduce_kernel, dim3(2048), dim3(256), 0, stream,
                       feats, sidx, sexp, binstart, S);
    hipLaunchKernelGGL(finalize_kernel, dim3(64), dim3(256), 0, stream, S, binstart, ESUM, Pyr);
    hipLaunchKernelGGL(gemm1_kernel, dim3(4, 101), dim3(256), 0, stream, Pyr, pW1, acc1);
    hipLaunchKernelGGL(gemm2_kernel, dim3(64), dim3(256), 0, stream, acc1, pb1, pW2, pb2, out);
}